// Round 8
// baseline (415.692 us; speedup 1.0000x reference)
//
#include <hip/hip_runtime.h>
#include <math.h>

#define B_ 16
#define L_ 4096
#define H_ 8
#define E_ 64
#define C_ 512     // H*E
#define K_ 24
#define NT 256
#define RPAD 257   // padded row stride (float2 units) for the 16x256 LDS matrix
#define WSZ 4112   // 16*RPAD, per-channel FFT work size (float2)

__device__ __forceinline__ float2 cmul(float2 a, float2 b) {
    return make_float2(a.x * b.x - a.y * b.y, a.x * b.y + a.y * b.x);
}
__device__ __forceinline__ float2 cadd(float2 a, float2 b) { return make_float2(a.x + b.x, a.y + b.y); }
__device__ __forceinline__ float2 csub(float2 a, float2 b) { return make_float2(a.x - b.x, a.y - b.y); }

// barrier that orders LDS only: does NOT drain vmcnt
__device__ __forceinline__ void bar_lds() {
    asm volatile("s_waitcnt lgkmcnt(0)" ::: "memory");
    __builtin_amdgcn_s_barrier();
}

// 16-point DIF FFT, natural-order input; output: X[k] = a[br4[k]]
__device__ __forceinline__ void fft16(float2 a[16]) {
    const float r2 = 0.70710678118654752f;
    const float c1 = 0.92387953251128676f;  // cos(pi/8)
    const float s1 = 0.38268343236508977f;  // sin(pi/8)
    const float2 W16[8] = {
        make_float2(1.f, 0.f),  make_float2(c1, -s1),  make_float2(r2, -r2),  make_float2(s1, -c1),
        make_float2(0.f, -1.f), make_float2(-s1, -c1), make_float2(-r2, -r2), make_float2(-c1, -s1)};
    #pragma unroll
    for (int j = 0; j < 8; ++j) {
        float2 u = a[j], v = a[j + 8];
        a[j]     = cadd(u, v);
        a[j + 8] = cmul(csub(u, v), W16[j]);
    }
    #pragma unroll
    for (int b = 0; b < 16; b += 8)
        #pragma unroll
        for (int j = 0; j < 4; ++j) {
            float2 u = a[b + j], v = a[b + j + 4];
            a[b + j]     = cadd(u, v);
            a[b + j + 4] = cmul(csub(u, v), W16[2 * j]);
        }
    #pragma unroll
    for (int b = 0; b < 16; b += 4)
        #pragma unroll
        for (int j = 0; j < 2; ++j) {
            float2 u = a[b + j], v = a[b + j + 2];
            a[b + j]     = cadd(u, v);
            a[b + j + 2] = cmul(csub(u, v), W16[4 * j]);
        }
    #pragma unroll
    for (int b = 0; b < 16; b += 2) {
        float2 u = a[b], v = a[b + 1];
        a[b]     = cadd(u, v);
        a[b + 1] = csub(u, v);
    }
}

// ---------------- zero scratch ----------------
__global__ __launch_bounds__(256) void k_zero(float* __restrict__ p, int n) {
    int i = blockIdx.x * 256 + threadIdx.x;
    if (i < n) p[i] = 0.f;
}

// ---------------- fused forward FFT + cross-spectrum (512t / 2ch / 2 blocks/CU) ----------------
// Round-7 post-mortem: 133KB LDS -> 1 block/CU -> zero inter-block overlap;
// staging latency + barriers + atomic drain fully exposed (VALUBusy 24%).
// This version: 512 threads (2 groups x 256), 2 channels, LDS 67.8KB ->
// 2 blocks/CU; one block's loads/atomics hide under the other's FFT.
// Liveness (round-7-verified): loads (32) die at staging; a[16] (32) dies
// before accumulate; acc (16) born after -> peak ~52 < 64-VGPR budget.
// Conjugate symmetry: S(L-p) = conj(S(p)) (Q,K = FFTs of real inputs), so
// accumulate + atomics only for bins 0..2048; k_ifft reconstructs the rest.
// Keeps atomic count at round-7 level (~16.8M) despite 2x blocks.
// Staging: 8B/lane q + k at 2KB stride; 16 consecutive co-XCD sibling blocks
// cover each 128B line -> L2 dedup (verified: round-7 FETCH = 131MB).
__global__ __launch_bounds__(512) void k_fft_full(const float* __restrict__ q,
                                                  const float* __restrict__ k,
                                                  float* __restrict__ cross) {
    __shared__ float2 w2[2 * WSZ];    // 65,792 B union: stg(64KB) / work / reduction
    __shared__ float2 tw256[256];     // tw256[r1*16+m2] = W256^{m2*r1}
    const int br4[16] = {0, 8, 4, 12, 2, 10, 6, 14, 1, 9, 5, 13, 3, 11, 7, 15};
    const int tid = threadIdx.x;      // 0..511
    const int t   = tid & 255;        // lane within group
    const int grp = tid >> 8;         // 0..1

    // XCD-aware bijective decode: 4096 blocks; xcd = id&7 owns 512 consecutive
    // wk (= 2 whole batches); consecutive g within a batch share lines.
    int id = blockIdx.x;
    int wk = ((id & 7) << 9) | (id >> 3);
    int b  = wk >> 8;                 // 0..15
    int g  = wk & 255;                // 2-channel group within batch
    int c0 = g << 1;

    if (tid < 256) {
        int r1 = tid >> 4, m2 = tid & 15;
        float sn, cs;
        sincospif((float)(r1 * m2) / 128.0f, &sn, &cs);
        tw256[tid] = make_float2(cs, -sn);
    }

    const int rowB = t >> 4, m2B = t & 15;
    const int k1C = t & 15, r1C = t >> 4;
    const int swl = (tid >> 4) & 1;   // ch-XOR swizzle term; == ((tau>>4)&1) at staging
    const int chx = grp ^ swl;

    // ---- issue the block's global loads (2 ch x 4096 tau, 8B q + 8B k per lane-iter)
    const size_t rowbase = (size_t)b * L_ * C_;
    float2 qr[8], kr[8];
    #pragma unroll
    for (int it = 0; it < 8; ++it) {
        int tau = (it << 9) + tid;
        qr[it] = *(const float2*)(q + rowbase + (size_t)tau * C_ + c0);
        kr[it] = *(const float2*)(k + rowbase + (size_t)tau * C_ + c0);
    }

    float2* wg = w2 + grp * WSZ;

    // ---- stage: z = q + i*k, stg[tau*2 + (j^sw)], sw = (tau>>4)&1 (qr/kr die here)
    #pragma unroll
    for (int it = 0; it < 8; ++it) {
        int tau = (it << 9) + tid;
        float2* row = w2 + (tau << 1);
        row[0 ^ swl] = make_float2(qr[it].x, kr[it].x);
        row[1 ^ swl] = make_float2(qr[it].y, kr[it].y);
    }
    __syncthreads();

    // ---- phase-A gather to registers (2-way bank aliasing = free) ----
    float2 a[16];
    #pragma unroll
    for (int n1 = 0; n1 < 16; ++n1)
        a[n1] = w2[(((n1 << 8) + t) << 1) + chx];
    bar_lds();   // every gather retired before phase-A writes overwrite stg

    // ---- phase A ----
    fft16(a);
    {
        float snA, csA;
        sincospif((float)t / 2048.0f, &snA, &csA);
        const float2 w1 = make_float2(csA, -snA);
        float2 tw = w1;
        wg[t] = a[0];                       // k1 = 0
        #pragma unroll
        for (int k1 = 1; k1 < 16; ++k1) {
            wg[k1 * RPAD + t] = cmul(a[br4[k1]], tw);
            tw = cmul(tw, w1);
        }
    }
    __syncthreads();
    // ---- phase B (in-place, cells thread-exclusive) ----
    #pragma unroll
    for (int m1 = 0; m1 < 16; ++m1) a[m1] = wg[rowB * RPAD + (m1 << 4) + m2B];
    fft16(a);
    #pragma unroll
    for (int r1 = 0; r1 < 16; ++r1)
        wg[rowB * RPAD + (r1 << 4) + m2B] = cmul(a[br4[r1]], tw256[(r1 << 4) + m2B]);
    __syncthreads();
    // ---- phase C ----
    #pragma unroll
    for (int m2 = 0; m2 < 16; ++m2) a[m2] = wg[k1C * RPAD + (r1C << 4) + m2];
    fft16(a);
    __syncthreads();
    #pragma unroll
    for (int r2 = 0; r2 < 16; ++r2)
        wg[(r2 << 8) + (r1C << 4) + k1C] = a[br4[r2]];   // natural order, flat
    bar_lds();

    // ---- unpack Z=Q+iK, accumulate S=Q*conj(K), HALF SPECTRUM p in [0,2047] ----
    float accx[8], accy[8];
    #pragma unroll
    for (int r = 0; r < 8; ++r) {
        int p  = t + (r << 8);
        int pp = (L_ - p) & (L_ - 1);
        float2 A  = wg[p];
        float2 Bv = wg[pp];
        float Qr = 0.5f * (A.x + Bv.x);
        float Qi = 0.5f * (A.y - Bv.y);
        float Kr = 0.5f * (A.y + Bv.y);
        float Ki = 0.5f * (A.x - Bv.x);
        accx[r] = Qr * Kr - Qi * Ki;
        accy[r] = Qr * Ki + Qi * Kr;
    }
    // bin 2048 (self-conjugate: Q,K real there; S = Q*K, imag 0)
    float v2048 = 0.f;
    if (t == 0) v2048 = wg[2048].x * wg[2048].y;
    bar_lds();   // all accumulate reads done before transpose-store overwrites wg

    // ---- cross-group reduction in LDS (stride 9: coprime 32 -> conflict-free) ----
    #pragma unroll
    for (int r = 0; r < 8; ++r)
        wg[t * 9 + r] = make_float2(accx[r], accy[r]);
    __syncthreads();
    float* crb = cross + (size_t)b * L_ * 2;
    #pragma unroll
    for (int rr = 0; rr < 4; ++rr) {
        int p  = tid + (rr << 9);     // 0..2047
        int tl = p & 255, rv = p >> 8;
        float sx = 0.f, sy = 0.f;
        #pragma unroll
        for (int gg = 0; gg < 2; ++gg) {
            float2 vv = w2[gg * WSZ + tl * 9 + rv];
            sx += vv.x; sy += vv.y;
        }
        atomicAdd(&crb[p * 2 + 0], sx);
        atomicAdd(&crb[p * 2 + 1], sy);
    }
    if (t == 0) atomicAdd(&crb[2 * 2048], v2048);
}

// ---------------- inverse FFT via conj-forward 3-phase radix-16 ----------------
// cross holds only bins 0..2048; upper half reconstructed via S(L-p)=conj(S(p)).
__global__ __launch_bounds__(256) void k_ifft(const float* __restrict__ cross,
                                              float* __restrict__ mv) {
    __shared__ float2 s[16 * RPAD];
    __shared__ float2 tw256[256];
    const int br4[16] = {0, 8, 4, 12, 2, 10, 6, 14, 1, 9, 5, 13, 3, 11, 7, 15};
    int t = threadIdx.x;
    int b = blockIdx.x;
    {
        int r1 = t >> 4, m2 = t & 15;
        float sn, cs;
        sincospif((float)(r1 * m2) / 128.0f, &sn, &cs);
        tw256[t] = make_float2(cs, -sn);
    }
    const float2* cr = (const float2*)cross + (size_t)b * L_;
    float2 a[16];
    #pragma unroll
    for (int n1 = 0; n1 < 16; ++n1) {
        int P = (n1 << 8) + t;
        int hi = P > 2048;
        float2 v = cr[hi ? (L_ - P) : P];
        // want a = conj(S(P)): P<=2048 -> conj(v); P>2048 -> S(P)=conj(v) -> a = v
        a[n1] = hi ? v : make_float2(v.x, -v.y);
    }
    // ---- phase A ----
    fft16(a);
    {
        float sn, cs;
        sincospif((float)t / 2048.0f, &sn, &cs);
        const float2 w1 = make_float2(cs, -sn);
        float2 tw = w1;
        s[t] = a[0];
        #pragma unroll
        for (int k1 = 1; k1 < 16; ++k1) {
            s[k1 * RPAD + t] = cmul(a[br4[k1]], tw);
            tw = cmul(tw, w1);
        }
    }
    __syncthreads();
    // ---- phase B ----
    const int rowB = t >> 4, m2B = t & 15;
    #pragma unroll
    for (int m1 = 0; m1 < 16; ++m1) a[m1] = s[rowB * RPAD + (m1 << 4) + m2B];
    fft16(a);
    #pragma unroll
    for (int r1 = 0; r1 < 16; ++r1)
        s[rowB * RPAD + (r1 << 4) + m2B] = cmul(a[br4[r1]], tw256[(r1 << 4) + m2B]);
    __syncthreads();
    // ---- phase C: write mv directly (k = r2*256 + t, coalesced) ----
    const int k1C = t & 15, r1C = t >> 4;
    #pragma unroll
    for (int m2 = 0; m2 < 16; ++m2) a[m2] = s[k1C * RPAD + (r1C << 4) + m2];
    fft16(a);
    const float scale = 1.0f / ((float)L_ * (float)C_);
    #pragma unroll
    for (int r2 = 0; r2 < 16; ++r2)
        mv[(size_t)b * L_ + (r2 << 8) + t] = a[br4[r2]].x * scale;
}

// ---------------- top-24 + per-batch softmax (register-resident, wave-shuffle) ----------------
__global__ __launch_bounds__(256) void k_topk(const float* __restrict__ mv,
                                              int* __restrict__ idx,
                                              float* __restrict__ wts) {
    __shared__ float wv[4];
    __shared__ int   wi[4];
    __shared__ int   idxL[K_];
    int tid = threadIdx.x;
    float vloc[16];
    #pragma unroll
    for (int r = 0; r < 16; ++r) {
        int tt = tid + (r << 8);
        float ssum = 0.f;
        for (int b = 0; b < B_; ++b) ssum += mv[(size_t)b * L_ + tt];
        vloc[r] = ssum;
    }
    int lane = tid & 63, w = tid >> 6;
    for (int i = 0; i < K_; ++i) {
        float best = -INFINITY; int bi = 1 << 30;
        #pragma unroll
        for (int r = 0; r < 16; ++r) {
            float v = vloc[r]; int ii = tid + (r << 8);
            if (v > best || (v == best && ii < bi)) { best = v; bi = ii; }
        }
        #pragma unroll
        for (int off = 32; off > 0; off >>= 1) {
            float ov = __shfl_down(best, off);
            int   oi = __shfl_down(bi, off);
            if (ov > best || (ov == best && oi < bi)) { best = ov; bi = oi; }
        }
        if (lane == 0) { wv[w] = best; wi[w] = bi; }
        __syncthreads();
        if (tid == 0) {
            float bb = wv[0]; int bj = wi[0];
            for (int j = 1; j < 4; ++j)
                if (wv[j] > bb || (wv[j] == bb && wi[j] < bj)) { bb = wv[j]; bj = wi[j]; }
            idxL[i] = bj; idx[i] = bj;
        }
        __syncthreads();
        int win = idxL[i];
        #pragma unroll
        for (int r = 0; r < 16; ++r)
            if (win == tid + (r << 8)) vloc[r] = -INFINITY;
    }
    if (tid < B_) {
        int b = tid;
        float ww[K_]; float wm = -INFINITY;
        for (int i = 0; i < K_; ++i) { ww[i] = mv[(size_t)b * L_ + idxL[i]]; wm = fmaxf(wm, ww[i]); }
        float ssum = 0.f;
        for (int i = 0; i < K_; ++i) { ww[i] = expf(ww[i] - wm); ssum += ww[i]; }
        float inv = 1.f / ssum;
        for (int i = 0; i < K_; ++i) wts[b * K_ + i] = ww[i] * inv;
    }
}

// ---------------- 24-tap circulant gather-sum, LDS tau-ring version ----------------
__global__ __launch_bounds__(256) void k_agg(const float* __restrict__ vals,
                                             const int* __restrict__ idx,
                                             const float* __restrict__ wts,
                                             float* __restrict__ out) {
    __shared__ float4 sv[L_];      // 64 KB ring: 2 blocks/CU
    __shared__ int   di[K_];
    __shared__ float dw[K_];
    const int tid = threadIdx.x;
    // XCD-aware bijective decode: 2048 blocks; xcd = id&7 owns work [xcd*256, xcd*256+256)
    int id = blockIdx.x;
    int wk = ((id & 7) << 8) | (id >> 3);
    int b  = wk >> 7;              // 0..15 (2 batches per XCD)
    int c0 = (wk & 127) << 2;      // channel-quad start

    if (tid < K_) { di[tid] = idx[tid]; dw[tid] = wts[b * K_ + tid]; }

    // ---- stage: 16 iters x 256 lanes x 16B, LDS dest linear (wave-uniform base + lane*16)
    const float* gbase = vals + (size_t)b * L_ * C_ + c0;
    #pragma unroll
    for (int it = 0; it < 16; ++it) {
        int tau = (it << 8) + tid;
        const float* g = gbase + (size_t)tau * C_;
        float4* l = &sv[(it << 8) + ((tid >> 6) << 6)];   // wave-uniform within each wave
        __builtin_amdgcn_global_load_lds(
            (const __attribute__((address_space(1))) uint32_t*)g,
            (__attribute__((address_space(3))) uint32_t*)l,
            16, 0, 0);
    }
    __syncthreads();   // drains vmcnt before barrier

    // taps/weights to registers (fully-unrolled static indexing)
    int   dir[K_]; float dwr[K_];
    #pragma unroll
    for (int i = 0; i < K_; ++i) { dir[i] = di[i]; dwr[i] = dw[i]; }

    float* obase = out + (size_t)b * L_ * C_ + c0;
    for (int r = 0; r < 16; ++r) {
        int tau = (r << 8) + tid;
        float4 acc = make_float4(0.f, 0.f, 0.f, 0.f);
        #pragma unroll
        for (int i = 0; i < K_; ++i) {
            float4 x = sv[(tau + dir[i]) & (L_ - 1)];
            float w = dwr[i];
            acc.x = fmaf(w, x.x, acc.x);
            acc.y = fmaf(w, x.y, acc.y);
            acc.z = fmaf(w, x.z, acc.z);
            acc.w = fmaf(w, x.w, acc.w);
        }
        *(float4*)(obase + (size_t)tau * C_) = acc;
    }
}

extern "C" void kernel_launch(void* const* d_in, const int* in_sizes, int n_in,
                              void* d_out, int out_size, void* d_ws, size_t ws_size,
                              hipStream_t stream) {
    const float* q = (const float*)d_in[0];
    const float* k = (const float*)d_in[1];
    const float* v = (const float*)d_in[2];
    float* out = (float*)d_out;
    char* ws = (char*)d_ws;

    // ws layout: [cross 512KB | mv 256KB | idx | wts]  (no z: fully fused FFT)
    float* cross = (float*)ws;
    float* mv    = (float*)(ws + (1 << 20));
    int*   idx   = (int*)(ws + (1 << 20) + (1 << 18));
    float* wts   = (float*)(ws + (1 << 20) + (1 << 18) + 4096);

    k_zero<<<(B_ * L_ * 2 + 255) / 256, 256, 0, stream>>>(cross, B_ * L_ * 2);
    k_fft_full<<<B_ * (C_ / 2), 512, 0, stream>>>(q, k, cross);
    k_ifft<<<B_, 256, 0, stream>>>(cross, mv);
    k_topk<<<1, 256, 0, stream>>>(mv, idx, wts);
    k_agg<<<B_ * (C_ / 4), 256, 0, stream>>>(v, idx, wts, out);
}